// Round 10
// baseline (242.208 us; speedup 1.0000x reference)
//
#include <hip/hip_runtime.h>
#include <math.h>

// FourierCrossAttention: B=16, L=4096, H=8, E=EO=64, MODES=64 (lowest)
// R10: k1 rewritten k3-style: ZERO LDS, ZERO barriers. Dual formulation
// X^T[e][m'] = sum_t x^T[e][t] W^T[t][m']: A = x (built in registers from
// coalesced dword loads + in-reg fold + cvtpk), B = folded twiddle table
// (fragment-major, parity-grouped rows). Each wave owns a disjoint 16-e
// slice -> every x line read exactly once. S=4, 3 partial sets.

constexpr float TWOPI_L = 1.5339807878856412e-3f;  // 2*pi/4096

typedef __attribute__((ext_vector_type(8))) short short8;
typedef __attribute__((ext_vector_type(4))) float f32x4;

__device__ __forceinline__ unsigned short f2bf(float f) {
    unsigned int u = __builtin_bit_cast(unsigned int, f);
    unsigned int r = (u + 0x7fffu + ((u >> 16) & 1u)) >> 16;
    return (unsigned short)r;
}
__device__ __forceinline__ float bf2f(unsigned short h) {
    unsigned int u = ((unsigned int)h) << 16;
    return __builtin_bit_cast(float, u);
}
// packed RNE f32->bf16 pair: low16 = bf(a), high16 = bf(b)
__device__ __forceinline__ unsigned int cvtpk(float a, float b) {
    unsigned int r;
    asm("v_cvt_pk_bf16_f32 %0, %1, %2" : "=v"(r) : "v"(a), "v"(b));
    return r;
}
// build hi/lo short8 fragments from 8 floats (k-slots)
__device__ __forceinline__ void mk_frag(const float* v, short8& hi, short8& lo) {
    unsigned int hp[4], lp[4];
#pragma unroll
    for (int p = 0; p < 4; ++p) {
        hp[p] = cvtpk(v[2 * p], v[2 * p + 1]);
        const float h0 = __builtin_bit_cast(float, hp[p] << 16);
        const float h1 = __builtin_bit_cast(float, hp[p] & 0xffff0000u);
        lp[p] = cvtpk(v[2 * p] - h0, v[2 * p + 1] - h1);
    }
    hi = __builtin_bit_cast(short8, *(uint4*)hp);
    lo = __builtin_bit_cast(short8, *(uint4*)lp);
}

// ---------------- K0: folded twiddle table, fragment-major, parity-grouped ----------------
// Row r (0..127): nt=r>>4, l15=r&15, par=nt>>2, f=nt&3;
//   mode m = 2*(8*f + (l15>>1)) + par, comp c = l15&1 (0=cos, 1=-sin).
// Entry addr = (ksg*128 + r)*32 + tt, t = ksg*32 + tt (t < 2048).
__global__ __launch_bounds__(256) void k0_twiddle(unsigned short* __restrict__ Whi,
                                                  unsigned short* __restrict__ Wlo) {
    const int idx = blockIdx.x * 256 + threadIdx.x;   // 32768 threads x 8 entries
    const int ksg = idx >> 9;            // 0..63
    const int r = (idx >> 2) & 127;      // 0..127
    const int ttg = idx & 3;             // 0..3
    const int nt = r >> 4, l15 = r & 15;
    const int m = 2 * (8 * (nt & 3) + (l15 >> 1)) + (nt >> 2);
    const int c = l15 & 1;
    const int addr = (ksg * 128 + r) * 32 + ttg * 8;
    unsigned short hbuf[8], lbuf[8];
#pragma unroll
    for (int j = 0; j < 8; ++j) {
        const int t = ksg * 32 + ttg * 8 + j;
        float sv, cv;
        sincosf((float)((m * t) & 4095) * TWOPI_L, &sv, &cv);
        const float v = c ? -sv : cv;
        const unsigned short hi = f2bf(v);
        hbuf[j] = hi;
        lbuf[j] = f2bf(v - bf2f(hi));
    }
    *(uint4*)(Whi + addr) = *(uint4*)hbuf;
    *(uint4*)(Wlo + addr) = *(uint4*)lbuf;
}

// ---------------- K0b: irfft basis (bf16 hi only), written into ws (ex-Xq) ----------------
__global__ __launch_bounds__(256) void k0_basis(unsigned short* __restrict__ basis) {
    const int idx = blockIdx.x * 256 + threadIdx.x;   // 65536 threads x 4 pairs
    const int p0 = idx << 2;                          // (t,m) pair index
    const int t = p0 >> 6;
    unsigned int pk[4];
#pragma unroll
    for (int j = 0; j < 4; ++j) {
        const int m = (p0 & 63) + j;
        float sv, cv;
        sincosf((float)((m * t) & 4095) * TWOPI_L, &sv, &cv);
        const float c = (m == 0) ? 1.0f : 2.0f * cv;
        const float s = (m == 0) ? 0.0f : -2.0f * sv;
        pk[j] = (unsigned int)f2bf(c) | ((unsigned int)f2bf(s) << 16);
    }
    *(uint4*)(basis + (size_t)t * 128u + ((p0 & 63) << 1)) =
        make_uint4(pk[0], pk[1], pk[2], pk[3]);
}

// ---------------- K1: LDS-free folded MFMA DFT. X^T[64e][128 cols], K=512/block (S=4) ----------------
__global__ __launch_bounds__(256, 4) void k1_mfma(const float* __restrict__ q,
                                                  const float* __restrict__ kin,
                                                  const unsigned short* __restrict__ Whi,
                                                  const unsigned short* __restrict__ Wlo,
                                                  float* __restrict__ Xq, float* __restrict__ Xk,
                                                  float* __restrict__ Pq, float* __restrict__ Pk)
{
    const int tid = threadIdx.x;
    const int bid = blockIdx.x;
    const int bh = bid >> 3, src = (bid >> 2) & 1, seg = bid & 3;
    const int b = bh >> 3, h = bh & 7;
    const float* __restrict__ x = src ? kin : q;
    const float* xb = x + (size_t)b * 2097152u + (size_t)h * 64u;

    const int wid = tid >> 6, lane = tid & 63;
    const int l15 = lane & 15, lg = lane >> 4;
    const int ew = 16 * wid;                 // wave's e-slice base
    const float* xl = xb + (size_t)(ew + l15);

    f32x4 acc[8];
#pragma unroll
    for (int nt = 0; nt < 8; ++nt) acc[nt] = (f32x4){0.f, 0.f, 0.f, 0.f};

#pragma unroll 2
    for (int ks = 0; ks < 16; ++ks) {
        const int ksg = seg * 16 + ks;
        const int t0 = ksg * 32 + 8 * lg;
        // x loads: a[j] = x[t0+j][e], c[j] = x[t0+j+2048][e] (coalesced dwords)
        float a[8], c[8];
#pragma unroll
        for (int j = 0; j < 8; ++j) a[j] = xl[(size_t)(t0 + j) * 512u];
#pragma unroll
        for (int j = 0; j < 8; ++j) c[j] = xl[(size_t)(t0 + j + 2048) * 512u];
        // fold + convert to A fragments (in registers, no LDS)
        float xp[8], xm[8];
#pragma unroll
        for (int j = 0; j < 8; ++j) { xp[j] = a[j] + c[j]; xm[j] = a[j] - c[j]; }
        short8 Ahp, Alp, Ahm, Alm;
        mk_frag(xp, Ahp, Alp);
        mk_frag(xm, Ahm, Alm);
        // B loads (fragment-major, 16B/lane dense) + 3-pass MFMA per nt
        const unsigned short* Wb = Whi + (size_t)(ksg * 128) * 32u + (size_t)(8 * lg);
        const unsigned short* Wl = Wlo + (size_t)(ksg * 128) * 32u + (size_t)(8 * lg);
#pragma unroll
        for (int nt = 0; nt < 8; ++nt) {
            const size_t ro = (size_t)((nt * 16 + l15) * 32);
            const short8 Bh = *(const short8*)(Wb + ro);
            const short8 Bl = *(const short8*)(Wl + ro);
            const short8 Ah = (nt < 4) ? Ahp : Ahm;
            const short8 Al = (nt < 4) ? Alp : Alm;
            acc[nt] = __builtin_amdgcn_mfma_f32_16x16x32_bf16(Ah, Bh, acc[nt], 0, 0, 0);
            acc[nt] = __builtin_amdgcn_mfma_f32_16x16x32_bf16(Ah, Bl, acc[nt], 0, 0, 0);
            acc[nt] = __builtin_amdgcn_mfma_f32_16x16x32_bf16(Al, Bh, acc[nt], 0, 0, 0);
        }
    }

    // C-write: D row = e_local = 4*lg + reg, col l15 -> storage col
    // col_st = 32*(nt&3) + 2*(nt>>2) + 4*(l15>>1) + (l15&1); X layout [e][128] unchanged.
    float* Xd;
    if (seg == 0) Xd = src ? Xk : Xq;
    else          Xd = (src ? Pk : Pq) + (size_t)(seg - 1) * 1048576u;
    Xd += (size_t)bh * 8192u;
    const int col_base = 4 * (l15 >> 1) + (l15 & 1);
#pragma unroll
    for (int nt = 0; nt < 8; ++nt) {
        const int col = 32 * (nt & 3) + 2 * (nt >> 2) + col_base;
#pragma unroll
        for (int reg = 0; reg < 4; ++reg) {
            const int e = ew + 4 * lg + reg;
            Xd[(size_t)e * 128u + col] = acc[nt][reg];
        }
    }
}

// ---------------- K1b: reduce the 3 K-split partial sets into main ----------------
__global__ __launch_bounds__(256) void k1_reduce(float* __restrict__ Xq, const float* __restrict__ Pq,
                                                 float* __restrict__ Xk, const float* __restrict__ Pk) {
    const int i = blockIdx.x * 256 + threadIdx.x;   // 262144 float4s per array
    float4* a = (float4*)Xq;
    float4* c = (float4*)Xk;
    float4 v = a[i], w = c[i];
#pragma unroll
    for (int s = 0; s < 3; ++s) {
        const float4 p = ((const float4*)(Pq + (size_t)s * 1048576u))[i];
        const float4 r = ((const float4*)(Pk + (size_t)s * 1048576u))[i];
        v.x += p.x; v.y += p.y; v.z += p.z; v.w += p.w;
        w.x += r.x; w.y += r.y; w.z += r.z; w.w += r.w;
    }
    a[i] = v;
    c[i] = w;
}

// ---------------- K2a: P1  xqk = Xq^T . Xk (complex), tanh -> P[bh][y][2x] ----------------
__global__ __launch_bounds__(256) void k2a_p1(const float* __restrict__ Xq,
                                              const float* __restrict__ Xk,
                                              float* __restrict__ P)
{
    const int blk = blockIdx.x;
    const int bh = blk >> 2, xt = blk & 3;
    __shared__ float sQ[64 * 32];    // [e][2x-slice]
    __shared__ float sK[64 * 128];   // [e][2y]
    const int tid = threadIdx.x;
    const float* Xqb = Xq + (size_t)bh * 8192u;
    const float* Xkb = Xk + (size_t)bh * 8192u;

#pragma unroll
    for (int p = 0; p < 2; ++p) {
        const int f4 = tid + p * 256;           // 512 float4s
        const int row = f4 >> 3, c4 = f4 & 7;
        *(float4*)&sQ[row * 32 + c4 * 4] = *(const float4*)(Xqb + row * 128 + xt * 32 + c4 * 4);
    }
#pragma unroll
    for (int p = 0; p < 8; ++p) {
        const int f4 = tid + p * 256;           // 2048 float4s
        *(float4*)&sK[f4 * 4] = *(const float4*)(Xkb + f4 * 4);
    }
    __syncthreads();

    const int xg = tid & 15, yg = tid >> 4;
    float aR[4] = {0.f, 0.f, 0.f, 0.f}, aI[4] = {0.f, 0.f, 0.f, 0.f};
#pragma unroll 8
    for (int e = 0; e < 64; ++e) {
        const float2 qv = *(const float2*)&sQ[e * 32 + 2 * xg];
        const float4 k0 = *(const float4*)&sK[e * 128 + 8 * yg];
        const float4 k1v = *(const float4*)&sK[e * 128 + 8 * yg + 4];
        aR[0] += qv.x * k0.x - qv.y * k0.y;   aI[0] += qv.x * k0.y + qv.y * k0.x;
        aR[1] += qv.x * k0.z - qv.y * k0.w;   aI[1] += qv.x * k0.w + qv.y * k0.z;
        aR[2] += qv.x * k1v.x - qv.y * k1v.y; aI[2] += qv.x * k1v.y + qv.y * k1v.x;
        aR[3] += qv.x * k1v.z - qv.y * k1v.w; aI[3] += qv.x * k1v.w + qv.y * k1v.z;
    }
    float* Pb = P + (size_t)bh * 8192u;
    const int x_abs = xt * 16 + xg;
#pragma unroll
    for (int j = 0; j < 4; ++j) {
        const int y = 4 * yg + j;
        *(float2*)(Pb + (size_t)y * 128u + 2 * x_abs) =
            make_float2(tanhf(aR[j]), tanhf(aI[j]));
    }
}

// ---------------- K2b: P3  PV = P . Xk (complex over y) -> PVG[h][m][c][b][e] ----------------
__global__ __launch_bounds__(256) void k2b_p3(const float* __restrict__ P,
                                              const float* __restrict__ Xk,
                                              float* __restrict__ PVG)
{
    const int blk = blockIdx.x;
    const int bh = blk >> 2, et = blk & 3;
    const int b = bh >> 3, h = bh & 7;
    __shared__ float sP[64 * 128];   // [y][2x]
    __shared__ float sKe[16 * 132];  // [e_loc][2y] pad->132
    const int tid = threadIdx.x;
    const float* Pb = P + (size_t)bh * 8192u;
    const float* Xkb = Xk + (size_t)bh * 8192u + (size_t)(et * 16) * 128u;

#pragma unroll
    for (int p = 0; p < 8; ++p) {
        const int f4 = tid + p * 256;
        *(float4*)&sP[f4 * 4] = *(const float4*)(Pb + f4 * 4);
    }
#pragma unroll
    for (int p = 0; p < 2; ++p) {
        const int f4 = tid + p * 256;           // 512 float4s
        const int row = f4 >> 5, c4 = f4 & 31;
        *(float4*)&sKe[row * 132 + c4 * 4] = *(const float4*)(Xkb + row * 128 + c4 * 4);
    }
    __syncthreads();

    const int xg = tid & 15, el = tid >> 4;
    float aR[4] = {0.f, 0.f, 0.f, 0.f}, aI[4] = {0.f, 0.f, 0.f, 0.f};
#pragma unroll 8
    for (int y = 0; y < 64; ++y) {
        const float2 kv = *(const float2*)&sKe[el * 132 + 2 * y];
        const float4 p0 = *(const float4*)&sP[y * 128 + 8 * xg];
        const float4 p1 = *(const float4*)&sP[y * 128 + 8 * xg + 4];
        aR[0] += p0.x * kv.x - p0.y * kv.y;   aI[0] += p0.x * kv.y + p0.y * kv.x;
        aR[1] += p0.z * kv.x - p0.w * kv.y;   aI[1] += p0.z * kv.y + p0.w * kv.x;
        aR[2] += p1.x * kv.x - p1.y * kv.y;   aI[2] += p1.x * kv.y + p1.y * kv.x;
        aR[3] += p1.z * kv.x - p1.w * kv.y;   aI[3] += p1.z * kv.y + p1.w * kv.x;
    }
    const int e_abs = et * 16 + el;
    float* base = PVG + (size_t)h * 131072u;   // per h: 64m*2c*16b*64e
#pragma unroll
    for (int j = 0; j < 4; ++j) {
        const int m = 4 * xg + j;
        base[(size_t)m * 2048u + 0u    + (size_t)b * 64u + e_abs] = aR[j];
        base[(size_t)m * 2048u + 1024u + (size_t)b * 64u + e_abs] = aI[j];
    }
}

// ---------------- KWT: w1/w2 -> wT[h][m][e][2o] ----------------
__global__ __launch_bounds__(256) void kwt(const float* __restrict__ w1,
                                           const float* __restrict__ w2,
                                           float* __restrict__ wT)
{
    const int blk = blockIdx.x;     // h*64 + e
    const int h = blk >> 6, e = blk & 63;
    const int tid = threadIdx.x;
    const int m = tid & 63, oq = tid >> 6;   // o = oq*16 + i
    const float* w1b = w1 + ((size_t)(h * 64 + e)) * 4096u;
    const float* w2b = w2 + ((size_t)(h * 64 + e)) * 4096u;
    float buf[32];
#pragma unroll
    for (int i = 0; i < 16; ++i) {
        const int o = oq * 16 + i;
        buf[2 * i]     = w1b[o * 64 + m];
        buf[2 * i + 1] = w2b[o * 64 + m];
    }
    float* dst = wT + (((size_t)(h * 64 + m)) * 64u + e) * 128u + oq * 32;
#pragma unroll
    for (int i = 0; i < 8; ++i)
        *(float4*)(dst + i * 4) = *(float4*)&buf[i * 4];
}

// ---------------- K2c: P4  XW = PV . (w1 + i w2) -> XWT hi/lo bf16 ----------------
__global__ __launch_bounds__(256) void k2c_p4(const float* __restrict__ PVG,
                                              const float* __restrict__ wT,
                                              unsigned short* __restrict__ XWThi,
                                              unsigned short* __restrict__ XWTlo)
{
    const int blk = blockIdx.x;       // h*64 + m
    const int h = blk >> 6, m = blk & 63;
    __shared__ float sA[32 * 68];     // [c*16+b][e pad 68]
    __shared__ float sW[64 * 128];    // [e][2o]
    const int tid = threadIdx.x;
    const float* Ab = PVG + (size_t)h * 131072u + (size_t)m * 2048u;
    const float* Wb = wT + ((size_t)h * 64u + m) * 8192u;

#pragma unroll
    for (int p = 0; p < 2; ++p) {
        const int f4 = tid + p * 256;           // 512 float4s
        const int row = f4 >> 4, e0 = (f4 & 15) * 4;
        *(float4*)&sA[row * 68 + e0] = *(const float4*)(Ab + row * 64 + e0);
    }
#pragma unroll
    for (int p = 0; p < 8; ++p) {
        const int f4 = tid + p * 256;
        *(float4*)&sW[f4 * 4] = *(const float4*)(Wb + f4 * 4);
    }
    __syncthreads();

    const int og = tid & 15, b = tid >> 4;
    float aR[4] = {0.f, 0.f, 0.f, 0.f}, aI[4] = {0.f, 0.f, 0.f, 0.f};
#pragma unroll 8
    for (int e = 0; e < 64; ++e) {
        const float pR = sA[b * 68 + e];
        const float pI = sA[(16 + b) * 68 + e];
        const float4 w0 = *(const float4*)&sW[e * 128 + 8 * og];
        const float4 w1v = *(const float4*)&sW[e * 128 + 8 * og + 4];
        aR[0] += pR * w0.x - pI * w0.y;   aI[0] += pR * w0.y + pI * w0.x;
        aR[1] += pR * w0.z - pI * w0.w;   aI[1] += pR * w0.w + pI * w0.z;
        aR[2] += pR * w1v.x - pI * w1v.y; aI[2] += pR * w1v.y + pI * w1v.x;
        aR[3] += pR * w1v.z - pI * w1v.w; aI[3] += pR * w1v.w + pI * w1v.z;
    }
    const int bh = b * 8 + h;
    unsigned short* Th = XWThi + (size_t)bh * 8192u;
    unsigned short* Tl = XWTlo + (size_t)bh * 8192u;
#pragma unroll
    for (int j = 0; j < 4; ++j) {
        const int o = 4 * og + j;
        const unsigned int hp = cvtpk(aR[j], aI[j]);
        const float hR = __builtin_bit_cast(float, hp << 16);
        const float hI = __builtin_bit_cast(float, hp & 0xffff0000u);
        const unsigned int lp = cvtpk(aR[j] - hR, aI[j] - hI);
        *(unsigned int*)(Th + (size_t)o * 128u + 2 * m) = hp;
        *(unsigned int*)(Tl + (size_t)o * 128u + 2 * m) = lp;
    }
}

// ---------------- K3: MFMA irfft  out[4096t x 64o] = basis[4096x128] * XWT^T ----------------
__global__ __launch_bounds__(256, 3) void k3_mfma(const unsigned short* __restrict__ basis,
                                                  const unsigned short* __restrict__ XWThi,
                                                  const unsigned short* __restrict__ XWTlo,
                                                  float* __restrict__ out)
{
    const int bid = blockIdx.x;
    const int bh = bid >> 4, tc = bid & 15;
    const int b = bh >> 3, h = bh & 7;
    const int tid = threadIdx.x;
    const int wid = tid >> 6, lane = tid & 63;
    const int l15 = lane & 15, lg = lane >> 4;

    const int t0 = tc * 256 + wid * 64;
    const unsigned short* Th = XWThi + (size_t)bh * 8192u;
    const unsigned short* Tl = XWTlo + (size_t)bh * 8192u;

    f32x4 acc[4][4];
#pragma unroll
    for (int mt = 0; mt < 4; ++mt)
#pragma unroll
        for (int nt = 0; nt < 4; ++nt)
            acc[mt][nt] = (f32x4){0.f, 0.f, 0.f, 0.f};

#pragma unroll
    for (int ks = 0; ks < 4; ++ks) {
        const int ko = ks * 32 + 8 * lg;
        short8 A[4], Bh[4], Bl[4];
#pragma unroll
        for (int mt = 0; mt < 4; ++mt)
            A[mt] = *(const short8*)(basis + (size_t)(t0 + mt * 16 + l15) * 128u + ko);
#pragma unroll
        for (int nt = 0; nt < 4; ++nt) {
            Bh[nt] = *(const short8*)(Th + (size_t)(nt * 16 + l15) * 128u + ko);
            Bl[nt] = *(const short8*)(Tl + (size_t)(nt * 16 + l15) * 128u + ko);
        }
#pragma unroll
        for (int mt = 0; mt < 4; ++mt)
#pragma unroll
            for (int nt = 0; nt < 4; ++nt)
                acc[mt][nt] = __builtin_amdgcn_mfma_f32_16x16x32_bf16(A[mt], Bh[nt], acc[mt][nt], 0, 0, 0);
#pragma unroll
        for (int mt = 0; mt < 4; ++mt)
#pragma unroll
            for (int nt = 0; nt < 4; ++nt)
                acc[mt][nt] = __builtin_amdgcn_mfma_f32_16x16x32_bf16(A[mt], Bl[nt], acc[mt][nt], 0, 0, 0);
    }

    const float scale = 9.313225746154785e-10f;  // 2^-30
#pragma unroll
    for (int mt = 0; mt < 4; ++mt)
#pragma unroll
        for (int nt = 0; nt < 4; ++nt) {
            const int o = nt * 16 + l15;
#pragma unroll
            for (int j = 0; j < 4; ++j) {
                const int t = t0 + mt * 16 + 4 * lg + j;
                out[((size_t)(b * 4096 + t) * 8u + (size_t)h) * 64u + o] = acc[mt][nt][j] * scale;
            }
        }
}

extern "C" void kernel_launch(void* const* d_in, const int* in_sizes, int n_in,
                              void* d_out, int out_size, void* d_ws, size_t ws_size,
                              hipStream_t stream) {
    (void)in_sizes; (void)n_in; (void)out_size; (void)ws_size;
    const float* q  = (const float*)d_in[0];
    const float* k  = (const float*)d_in[1];
    // d_in[2] = v: unused by the reference forward
    const float* w1 = (const float*)d_in[3];
    const float* w2 = (const float*)d_in[4];
    float* out = (float*)d_out;

    // ws (12 MB): Xq [0,4MB) fl, Xk [4,8MB) fl, XWThi/lo [8,12MB) as bf16
    float* ws = (float*)d_ws;
    float* Xq = ws;
    float* Xk = ws + 1048576;
    unsigned short* XWThi = (unsigned short*)(ws + 2097152);   // 1,048,576 shorts
    unsigned short* XWTlo = XWThi + 1048576;
    unsigned short* basis = (unsigned short*)ws;               // overlays Xq AFTER k2a

    // d_out scratch (33.5M floats; all regions dead before k3 overwrites):
    unsigned short* Whi = (unsigned short*)out;                // 262,144 shorts (folded table)
    unsigned short* Wlo = Whi + 262144;                        // 262,144 shorts
    float* Pq  = out + 524288;                                 // 3 x 1M fl
    float* Pk  = out + 3670016;                                // 3 x 1M fl -> ends 6,815,744
    float* P   = out + 16777216;                               // 1M fl  (tanh'd xqk, [y][2x])
    float* wT  = out + 17825792;                               // 4M fl  [h][m][e][2o] -> 22,020,096
    float* PVG = out + 22020096;                               // 1M fl  [h][m][c][b][e]

    hipLaunchKernelGGL(k0_twiddle, dim3(128),  dim3(256), 0, stream, Whi, Wlo);
    hipLaunchKernelGGL(k1_mfma,    dim3(1024), dim3(256), 0, stream, q, k, Whi, Wlo, Xq, Xk, Pq, Pk);
    hipLaunchKernelGGL(k1_reduce,  dim3(1024), dim3(256), 0, stream, Xq, Pq, Xk, Pk);
    hipLaunchKernelGGL(k2a_p1,     dim3(512),  dim3(256), 0, stream, Xq, Xk, P);
    hipLaunchKernelGGL(k0_basis,   dim3(256),  dim3(256), 0, stream, basis);
    hipLaunchKernelGGL(k2b_p3,     dim3(512),  dim3(256), 0, stream, P, Xk, PVG);
    hipLaunchKernelGGL(kwt,        dim3(512),  dim3(256), 0, stream, w1, w2, wT);
    hipLaunchKernelGGL(k2c_p4,     dim3(512),  dim3(256), 0, stream, PVG, wT, XWThi, XWTlo);
    hipLaunchKernelGGL(k3_mfma,    dim3(2048), dim3(256), 0, stream, basis, XWThi, XWTlo, out);
}

// Round 11
// 239.107 us; speedup vs baseline: 1.0130x; 1.0130x over previous
//
#include <hip/hip_runtime.h>
#include <math.h>

// FourierCrossAttention: B=16, L=4096, H=8, E=EO=64, MODES=64 (lowest)
// R11: root cause of the 135us k1 invariant (R4-R10): compiler allocates
// 56-64 VGPRs (occupancy-first scheduling) -> can't keep loads in flight ->
// every iteration serializes into ~20 memory round-trips. Fix: ILP-first:
// __launch_bounds__(256,2) (cap 256 VGPR) + explicit 2-deep pipeline with
// static register sets + sched_barrier(0) pinning load issue order.
// Same accumulation order as R10 -> bit-identical output.

constexpr float TWOPI_L = 1.5339807878856412e-3f;  // 2*pi/4096

typedef __attribute__((ext_vector_type(8))) short short8;
typedef __attribute__((ext_vector_type(4))) float f32x4;

__device__ __forceinline__ unsigned short f2bf(float f) {
    unsigned int u = __builtin_bit_cast(unsigned int, f);
    unsigned int r = (u + 0x7fffu + ((u >> 16) & 1u)) >> 16;
    return (unsigned short)r;
}
__device__ __forceinline__ float bf2f(unsigned short h) {
    unsigned int u = ((unsigned int)h) << 16;
    return __builtin_bit_cast(float, u);
}
// packed RNE f32->bf16 pair: low16 = bf(a), high16 = bf(b)
__device__ __forceinline__ unsigned int cvtpk(float a, float b) {
    unsigned int r;
    asm("v_cvt_pk_bf16_f32 %0, %1, %2" : "=v"(r) : "v"(a), "v"(b));
    return r;
}
// build hi/lo short8 fragments from 8 floats (k-slots)
__device__ __forceinline__ void mk_frag(const float* v, short8& hi, short8& lo) {
    unsigned int hp[4], lp[4];
#pragma unroll
    for (int p = 0; p < 4; ++p) {
        hp[p] = cvtpk(v[2 * p], v[2 * p + 1]);
        const float h0 = __builtin_bit_cast(float, hp[p] << 16);
        const float h1 = __builtin_bit_cast(float, hp[p] & 0xffff0000u);
        lp[p] = cvtpk(v[2 * p] - h0, v[2 * p + 1] - h1);
    }
    hi = __builtin_bit_cast(short8, *(uint4*)hp);
    lo = __builtin_bit_cast(short8, *(uint4*)lp);
}

// ---------------- K0: folded twiddle table, fragment-major, parity-grouped ----------------
// Row r (0..127): nt=r>>4, l15=r&15; mode m = 2*(8*(nt&3) + (l15>>1)) + (nt>>2),
// comp c = l15&1 (0=cos, 1=-sin). Entry addr = (ksg*128 + r)*32 + tt, t = ksg*32+tt.
__global__ __launch_bounds__(256) void k0_twiddle(unsigned short* __restrict__ Whi,
                                                  unsigned short* __restrict__ Wlo) {
    const int idx = blockIdx.x * 256 + threadIdx.x;   // 32768 threads x 8 entries
    const int ksg = idx >> 9;            // 0..63
    const int r = (idx >> 2) & 127;      // 0..127
    const int ttg = idx & 3;             // 0..3
    const int nt = r >> 4, l15 = r & 15;
    const int m = 2 * (8 * (nt & 3) + (l15 >> 1)) + (nt >> 2);
    const int c = l15 & 1;
    const int addr = (ksg * 128 + r) * 32 + ttg * 8;
    unsigned short hbuf[8], lbuf[8];
#pragma unroll
    for (int j = 0; j < 8; ++j) {
        const int t = ksg * 32 + ttg * 8 + j;
        float sv, cv;
        sincosf((float)((m * t) & 4095) * TWOPI_L, &sv, &cv);
        const float v = c ? -sv : cv;
        const unsigned short hi = f2bf(v);
        hbuf[j] = hi;
        lbuf[j] = f2bf(v - bf2f(hi));
    }
    *(uint4*)(Whi + addr) = *(uint4*)hbuf;
    *(uint4*)(Wlo + addr) = *(uint4*)lbuf;
}

// ---------------- K0b: irfft basis (bf16 hi only), written into ws (ex-Xq) ----------------
__global__ __launch_bounds__(256) void k0_basis(unsigned short* __restrict__ basis) {
    const int idx = blockIdx.x * 256 + threadIdx.x;   // 65536 threads x 4 pairs
    const int p0 = idx << 2;                          // (t,m) pair index
    const int t = p0 >> 6;
    unsigned int pk[4];
#pragma unroll
    for (int j = 0; j < 4; ++j) {
        const int m = (p0 & 63) + j;
        float sv, cv;
        sincosf((float)((m * t) & 4095) * TWOPI_L, &sv, &cv);
        const float c = (m == 0) ? 1.0f : 2.0f * cv;
        const float s = (m == 0) ? 0.0f : -2.0f * sv;
        pk[j] = (unsigned int)f2bf(c) | ((unsigned int)f2bf(s) << 16);
    }
    *(uint4*)(basis + (size_t)t * 128u + ((p0 & 63) << 1)) =
        make_uint4(pk[0], pk[1], pk[2], pk[3]);
}

// ---------------- K1: LDS-free folded MFMA DFT, ILP-pipelined. S=4 ----------------
__global__ __launch_bounds__(256, 2) void k1_mfma(const float* __restrict__ q,
                                                  const float* __restrict__ kin,
                                                  const unsigned short* __restrict__ Whi,
                                                  const unsigned short* __restrict__ Wlo,
                                                  float* __restrict__ Xq, float* __restrict__ Xk,
                                                  float* __restrict__ Pq, float* __restrict__ Pk)
{
    const int tid = threadIdx.x;
    const int bid = blockIdx.x;
    const int bh = bid >> 3, src = (bid >> 2) & 1, seg = bid & 3;
    const int b = bh >> 3, h = bh & 7;
    const float* __restrict__ x = src ? kin : q;
    const float* xb = x + (size_t)b * 2097152u + (size_t)h * 64u;

    const int wid = tid >> 6, lane = tid & 63;
    const int l15 = lane & 15, lg = lane >> 4;
    const int ew = 16 * wid;                 // wave's e-slice base
    const float* xl = xb + (size_t)(ew + l15);

    f32x4 acc[8];
#pragma unroll
    for (int nt = 0; nt < 8; ++nt) acc[nt] = (f32x4){0.f, 0.f, 0.f, 0.f};

    float Aa[8], Ac[8], Ba[8], Bc[8];

#define LOADX(Pa, Pc, IT) do {                                                 \
    const int t0_ = (seg * 16 + (IT)) * 32 + 8 * lg;                           \
    _Pragma("unroll")                                                          \
    for (int j = 0; j < 8; ++j) Pa[j] = xl[(size_t)(t0_ + j) * 512u];          \
    _Pragma("unroll")                                                          \
    for (int j = 0; j < 8; ++j) Pc[j] = xl[(size_t)(t0_ + j + 2048) * 512u];   \
} while (0)

#define COMPUTE(Pa, Pc, IT) do {                                               \
    float xp_[8], xm_[8];                                                      \
    _Pragma("unroll")                                                          \
    for (int j = 0; j < 8; ++j) { xp_[j] = Pa[j] + Pc[j]; xm_[j] = Pa[j] - Pc[j]; } \
    short8 Ahp_, Alp_, Ahm_, Alm_;                                             \
    mk_frag(xp_, Ahp_, Alp_);                                                  \
    mk_frag(xm_, Ahm_, Alm_);                                                  \
    const unsigned short* Wb_ = Whi + (size_t)((seg * 16 + (IT)) * 128) * 32u + (size_t)(8 * lg); \
    const unsigned short* Wl_ = Wlo + (size_t)((seg * 16 + (IT)) * 128) * 32u + (size_t)(8 * lg); \
    _Pragma("unroll")                                                          \
    for (int nt = 0; nt < 8; ++nt) {                                           \
        const size_t ro_ = (size_t)((nt * 16 + l15) * 32);                     \
        const short8 Bh_ = *(const short8*)(Wb_ + ro_);                        \
        const short8 Bl_ = *(const short8*)(Wl_ + ro_);                        \
        const short8 Ah_ = (nt < 4) ? Ahp_ : Ahm_;                             \
        const short8 Al_ = (nt < 4) ? Alp_ : Alm_;                             \
        acc[nt] = __builtin_amdgcn_mfma_f32_16x16x32_bf16(Ah_, Bh_, acc[nt], 0, 0, 0); \
        acc[nt] = __builtin_amdgcn_mfma_f32_16x16x32_bf16(Ah_, Bl_, acc[nt], 0, 0, 0); \
        acc[nt] = __builtin_amdgcn_mfma_f32_16x16x32_bf16(Al_, Bh_, acc[nt], 0, 0, 0); \
    }                                                                          \
} while (0)

    // 2-deep software pipeline; sched_barrier(0) pins load issue ABOVE the
    // following compute (prevents the scheduler from re-serializing, cf. R8).
    LOADX(Aa, Ac, 0);
    for (int itp = 0; itp < 8; ++itp) {
        LOADX(Ba, Bc, 2 * itp + 1);
        __builtin_amdgcn_sched_barrier(0);
        COMPUTE(Aa, Ac, 2 * itp);
        if (itp < 7) {
            LOADX(Aa, Ac, 2 * itp + 2);
            __builtin_amdgcn_sched_barrier(0);
        }
        COMPUTE(Ba, Bc, 2 * itp + 1);
    }
#undef LOADX
#undef COMPUTE

    // C-write: D row = e_local = 4*lg + reg, col l15 -> storage col
    // col_st = 32*(nt&3) + 2*(nt>>2) + 4*(l15>>1) + (l15&1); X layout [e][128] unchanged.
    float* Xd;
    if (seg == 0) Xd = src ? Xk : Xq;
    else          Xd = (src ? Pk : Pq) + (size_t)(seg - 1) * 1048576u;
    Xd += (size_t)bh * 8192u;
    const int col_base = 4 * (l15 >> 1) + (l15 & 1);
#pragma unroll
    for (int nt = 0; nt < 8; ++nt) {
        const int col = 32 * (nt & 3) + 2 * (nt >> 2) + col_base;
#pragma unroll
        for (int reg = 0; reg < 4; ++reg) {
            const int e = ew + 4 * lg + reg;
            Xd[(size_t)e * 128u + col] = acc[nt][reg];
        }
    }
}

// ---------------- K1b: reduce the 3 K-split partial sets into main ----------------
__global__ __launch_bounds__(256) void k1_reduce(float* __restrict__ Xq, const float* __restrict__ Pq,
                                                 float* __restrict__ Xk, const float* __restrict__ Pk) {
    const int i = blockIdx.x * 256 + threadIdx.x;   // 262144 float4s per array
    float4* a = (float4*)Xq;
    float4* c = (float4*)Xk;
    float4 v = a[i], w = c[i];
#pragma unroll
    for (int s = 0; s < 3; ++s) {
        const float4 p = ((const float4*)(Pq + (size_t)s * 1048576u))[i];
        const float4 r = ((const float4*)(Pk + (size_t)s * 1048576u))[i];
        v.x += p.x; v.y += p.y; v.z += p.z; v.w += p.w;
        w.x += r.x; w.y += r.y; w.z += r.z; w.w += r.w;
    }
    a[i] = v;
    c[i] = w;
}

// ---------------- K2a: P1  xqk = Xq^T . Xk (complex), tanh -> P[bh][y][2x] ----------------
__global__ __launch_bounds__(256) void k2a_p1(const float* __restrict__ Xq,
                                              const float* __restrict__ Xk,
                                              float* __restrict__ P)
{
    const int blk = blockIdx.x;
    const int bh = blk >> 2, xt = blk & 3;
    __shared__ float sQ[64 * 32];    // [e][2x-slice]
    __shared__ float sK[64 * 128];   // [e][2y]
    const int tid = threadIdx.x;
    const float* Xqb = Xq + (size_t)bh * 8192u;
    const float* Xkb = Xk + (size_t)bh * 8192u;

#pragma unroll
    for (int p = 0; p < 2; ++p) {
        const int f4 = tid + p * 256;           // 512 float4s
        const int row = f4 >> 3, c4 = f4 & 7;
        *(float4*)&sQ[row * 32 + c4 * 4] = *(const float4*)(Xqb + row * 128 + xt * 32 + c4 * 4);
    }
#pragma unroll
    for (int p = 0; p < 8; ++p) {
        const int f4 = tid + p * 256;           // 2048 float4s
        *(float4*)&sK[f4 * 4] = *(const float4*)(Xkb + f4 * 4);
    }
    __syncthreads();

    const int xg = tid & 15, yg = tid >> 4;
    float aR[4] = {0.f, 0.f, 0.f, 0.f}, aI[4] = {0.f, 0.f, 0.f, 0.f};
#pragma unroll 8
    for (int e = 0; e < 64; ++e) {
        const float2 qv = *(const float2*)&sQ[e * 32 + 2 * xg];
        const float4 k0 = *(const float4*)&sK[e * 128 + 8 * yg];
        const float4 k1v = *(const float4*)&sK[e * 128 + 8 * yg + 4];
        aR[0] += qv.x * k0.x - qv.y * k0.y;   aI[0] += qv.x * k0.y + qv.y * k0.x;
        aR[1] += qv.x * k0.z - qv.y * k0.w;   aI[1] += qv.x * k0.w + qv.y * k0.z;
        aR[2] += qv.x * k1v.x - qv.y * k1v.y; aI[2] += qv.x * k1v.y + qv.y * k1v.x;
        aR[3] += qv.x * k1v.z - qv.y * k1v.w; aI[3] += qv.x * k1v.w + qv.y * k1v.z;
    }
    float* Pb = P + (size_t)bh * 8192u;
    const int x_abs = xt * 16 + xg;
#pragma unroll
    for (int j = 0; j < 4; ++j) {
        const int y = 4 * yg + j;
        *(float2*)(Pb + (size_t)y * 128u + 2 * x_abs) =
            make_float2(tanhf(aR[j]), tanhf(aI[j]));
    }
}

// ---------------- K2b: P3  PV = P . Xk (complex over y) -> PVG[h][m][c][b][e] ----------------
__global__ __launch_bounds__(256) void k2b_p3(const float* __restrict__ P,
                                              const float* __restrict__ Xk,
                                              float* __restrict__ PVG)
{
    const int blk = blockIdx.x;
    const int bh = blk >> 2, et = blk & 3;
    const int b = bh >> 3, h = bh & 7;
    __shared__ float sP[64 * 128];   // [y][2x]
    __shared__ float sKe[16 * 132];  // [e_loc][2y] pad->132
    const int tid = threadIdx.x;
    const float* Pb = P + (size_t)bh * 8192u;
    const float* Xkb = Xk + (size_t)bh * 8192u + (size_t)(et * 16) * 128u;

#pragma unroll
    for (int p = 0; p < 8; ++p) {
        const int f4 = tid + p * 256;
        *(float4*)&sP[f4 * 4] = *(const float4*)(Pb + f4 * 4);
    }
#pragma unroll
    for (int p = 0; p < 2; ++p) {
        const int f4 = tid + p * 256;           // 512 float4s
        const int row = f4 >> 5, c4 = f4 & 31;
        *(float4*)&sKe[row * 132 + c4 * 4] = *(const float4*)(Xkb + row * 128 + c4 * 4);
    }
    __syncthreads();

    const int xg = tid & 15, el = tid >> 4;
    float aR[4] = {0.f, 0.f, 0.f, 0.f}, aI[4] = {0.f, 0.f, 0.f, 0.f};
#pragma unroll 8
    for (int y = 0; y < 64; ++y) {
        const float2 kv = *(const float2*)&sKe[el * 132 + 2 * y];
        const float4 p0 = *(const float4*)&sP[y * 128 + 8 * xg];
        const float4 p1 = *(const float4*)&sP[y * 128 + 8 * xg + 4];
        aR[0] += p0.x * kv.x - p0.y * kv.y;   aI[0] += p0.x * kv.y + p0.y * kv.x;
        aR[1] += p0.z * kv.x - p0.w * kv.y;   aI[1] += p0.z * kv.y + p0.w * kv.x;
        aR[2] += p1.x * kv.x - p1.y * kv.y;   aI[2] += p1.x * kv.y + p1.y * kv.x;
        aR[3] += p1.z * kv.x - p1.w * kv.y;   aI[3] += p1.z * kv.y + p1.w * kv.x;
    }
    const int e_abs = et * 16 + el;
    float* base = PVG + (size_t)h * 131072u;   // per h: 64m*2c*16b*64e
#pragma unroll
    for (int j = 0; j < 4; ++j) {
        const int m = 4 * xg + j;
        base[(size_t)m * 2048u + 0u    + (size_t)b * 64u + e_abs] = aR[j];
        base[(size_t)m * 2048u + 1024u + (size_t)b * 64u + e_abs] = aI[j];
    }
}

// ---------------- KWT: w1/w2 -> wT[h][m][e][2o] ----------------
__global__ __launch_bounds__(256) void kwt(const float* __restrict__ w1,
                                           const float* __restrict__ w2,
                                           float* __restrict__ wT)
{
    const int blk = blockIdx.x;     // h*64 + e
    const int h = blk >> 6, e = blk & 63;
    const int tid = threadIdx.x;
    const int m = tid & 63, oq = tid >> 6;   // o = oq*16 + i
    const float* w1b = w1 + ((size_t)(h * 64 + e)) * 4096u;
    const float* w2b = w2 + ((size_t)(h * 64 + e)) * 4096u;
    float buf[32];
#pragma unroll
    for (int i = 0; i < 16; ++i) {
        const int o = oq * 16 + i;
        buf[2 * i]     = w1b[o * 64 + m];
        buf[2 * i + 1] = w2b[o * 64 + m];
    }
    float* dst = wT + (((size_t)(h * 64 + m)) * 64u + e) * 128u + oq * 32;
#pragma unroll
    for (int i = 0; i < 8; ++i)
        *(float4*)(dst + i * 4) = *(float4*)&buf[i * 4];
}

// ---------------- K2c: P4  XW = PV . (w1 + i w2) -> XWT hi/lo bf16 ----------------
__global__ __launch_bounds__(256) void k2c_p4(const float* __restrict__ PVG,
                                              const float* __restrict__ wT,
                                              unsigned short* __restrict__ XWThi,
                                              unsigned short* __restrict__ XWTlo)
{
    const int blk = blockIdx.x;       // h*64 + m
    const int h = blk >> 6, m = blk & 63;
    __shared__ float sA[32 * 68];     // [c*16+b][e pad 68]
    __shared__ float sW[64 * 128];    // [e][2o]
    const int tid = threadIdx.x;
    const float* Ab = PVG + (size_t)h * 131072u + (size_t)m * 2048u;
    const float* Wb = wT + ((size_t)h * 64u + m) * 8192u;

#pragma unroll
    for (int p = 0; p < 2; ++p) {
        const int f4 = tid + p * 256;           // 512 float4s
        const int row = f4 >> 4, e0 = (f4 & 15) * 4;
        *(float4*)&sA[row * 68 + e0] = *(const float4*)(Ab + row * 64 + e0);
    }
#pragma unroll
    for (int p = 0; p < 8; ++p) {
        const int f4 = tid + p * 256;
        *(float4*)&sW[f4 * 4] = *(const float4*)(Wb + f4 * 4);
    }
    __syncthreads();

    const int og = tid & 15, b = tid >> 4;
    float aR[4] = {0.f, 0.f, 0.f, 0.f}, aI[4] = {0.f, 0.f, 0.f, 0.f};
#pragma unroll 8
    for (int e = 0; e < 64; ++e) {
        const float pR = sA[b * 68 + e];
        const float pI = sA[(16 + b) * 68 + e];
        const float4 w0 = *(const float4*)&sW[e * 128 + 8 * og];
        const float4 w1v = *(const float4*)&sW[e * 128 + 8 * og + 4];
        aR[0] += pR * w0.x - pI * w0.y;   aI[0] += pR * w0.y + pI * w0.x;
        aR[1] += pR * w0.z - pI * w0.w;   aI[1] += pR * w0.w + pI * w0.z;
        aR[2] += pR * w1v.x - pI * w1v.y; aI[2] += pR * w1v.y + pI * w1v.x;
        aR[3] += pR * w1v.z - pI * w1v.w; aI[3] += pR * w1v.w + pI * w1v.z;
    }
    const int bh = b * 8 + h;
    unsigned short* Th = XWThi + (size_t)bh * 8192u;
    unsigned short* Tl = XWTlo + (size_t)bh * 8192u;
#pragma unroll
    for (int j = 0; j < 4; ++j) {
        const int o = 4 * og + j;
        const unsigned int hp = cvtpk(aR[j], aI[j]);
        const float hR = __builtin_bit_cast(float, hp << 16);
        const float hI = __builtin_bit_cast(float, hp & 0xffff0000u);
        const unsigned int lp = cvtpk(aR[j] - hR, aI[j] - hI);
        *(unsigned int*)(Th + (size_t)o * 128u + 2 * m) = hp;
        *(unsigned int*)(Tl + (size_t)o * 128u + 2 * m) = lp;
    }
}

// ---------------- K3: MFMA irfft  out[4096t x 64o] = basis[4096x128] * XWT^T ----------------
__global__ __launch_bounds__(256, 3) void k3_mfma(const unsigned short* __restrict__ basis,
                                                  const unsigned short* __restrict__ XWThi,
                                                  const unsigned short* __restrict__ XWTlo,
                                                  float* __restrict__ out)
{
    const int bid = blockIdx.x;
    const int bh = bid >> 4, tc = bid & 15;
    const int b = bh >> 3, h = bh & 7;
    const int tid = threadIdx.x;
    const int wid = tid >> 6, lane = tid & 63;
    const int l15 = lane & 15, lg = lane >> 4;

    const int t0 = tc * 256 + wid * 64;
    const unsigned short* Th = XWThi + (size_t)bh * 8192u;
    const unsigned short* Tl = XWTlo + (size_t)bh * 8192u;

    f32x4 acc[4][4];
#pragma unroll
    for (int mt = 0; mt < 4; ++mt)
#pragma unroll
        for (int nt = 0; nt < 4; ++nt)
            acc[mt][nt] = (f32x4){0.f, 0.f, 0.f, 0.f};

#pragma unroll
    for (int ks = 0; ks < 4; ++ks) {
        const int ko = ks * 32 + 8 * lg;
        short8 A[4], Bh[4], Bl[4];
#pragma unroll
        for (int mt = 0; mt < 4; ++mt)
            A[mt] = *(const short8*)(basis + (size_t)(t0 + mt * 16 + l15) * 128u + ko);
#pragma unroll
        for (int nt = 0; nt < 4; ++nt) {
            Bh[nt] = *(const short8*)(Th + (size_t)(nt * 16 + l15) * 128u + ko);
            Bl[nt] = *(const short8*)(Tl + (size_t)(nt * 16 + l15) * 128u + ko);
        }
#pragma unroll
        for (int mt = 0; mt < 4; ++mt)
#pragma unroll
            for (int nt = 0; nt < 4; ++nt)
                acc[mt][nt] = __builtin_amdgcn_mfma_f32_16x16x32_bf16(A[mt], Bh[nt], acc[mt][nt], 0, 0, 0);
#pragma unroll
        for (int mt = 0; mt < 4; ++mt)
#pragma unroll
            for (int nt = 0; nt < 4; ++nt)
                acc[mt][nt] = __builtin_amdgcn_mfma_f32_16x16x32_bf16(A[mt], Bl[nt], acc[mt][nt], 0, 0, 0);
    }

    const float scale = 9.313225746154785e-10f;  // 2^-30
#pragma unroll
    for (int mt = 0; mt < 4; ++mt)
#pragma unroll
        for (int nt = 0; nt < 4; ++nt) {
            const int o = nt * 16 + l15;
#pragma unroll
            for (int j = 0; j < 4; ++j) {
                const int t = t0 + mt * 16 + 4 * lg + j;
                out[((size_t)(b * 4096 + t) * 8u + (size_t)h) * 64u + o] = acc[mt][nt][j] * scale;
            }
        }
}

extern "C" void kernel_launch(void* const* d_in, const int* in_sizes, int n_in,
                              void* d_out, int out_size, void* d_ws, size_t ws_size,
                              hipStream_t stream) {
    (void)in_sizes; (void)n_in; (void)out_size; (void)ws_size;
    const float* q  = (const float*)d_in[0];
    const float* k  = (const float*)d_in[1];
    // d_in[2] = v: unused by the reference forward
    const float* w1 = (const float*)d_in[3];
    const float* w2 = (const float*)d_in[4];
    float* out = (float*)d_out;

    // ws (12 MB): Xq [0,4MB) fl, Xk [4,8MB) fl, XWThi/lo [8,12MB) as bf16
    float* ws = (float*)d_ws;
    float* Xq = ws;
    float* Xk = ws + 1048576;
    unsigned short* XWThi = (unsigned short*)(ws + 2097152);   // 1,048,576 shorts
    unsigned short* XWTlo = XWThi + 1048576;
    unsigned short* basis = (unsigned short*)ws;               // overlays Xq AFTER k2a

    // d_out scratch (33.5M floats; all regions dead before k3 overwrites):
    unsigned short* Whi = (unsigned short*)out;                // 262,144 shorts (folded table)
    unsigned short* Wlo = Whi + 262144;                        // 262,144 shorts
    float* Pq  = out + 524288;                                 // 3 x 1M fl
    float* Pk  = out + 3670016;                                // 3 x 1M fl -> ends 6,815,744
    float* P   = out + 16777216;                               // 1M fl  (tanh'd xqk, [y][2x])
    float* wT  = out + 17825792;                               // 4M fl  [h][m][e][2o] -> 22,020,096
    float* PVG = out + 22020096;                               // 1M fl  [h][m][c][b][e]

    hipLaunchKernelGGL(k0_twiddle, dim3(128),  dim3(256), 0, stream, Whi, Wlo);
    hipLaunchKernelGGL(k1_mfma,    dim3(1024), dim3(256), 0, stream, q, k, Whi, Wlo, Xq, Xk, Pq, Pk);
    hipLaunchKernelGGL(k1_reduce,  dim3(1024), dim3(256), 0, stream, Xq, Pq, Xk, Pk);
    hipLaunchKernelGGL(k2a_p1,     dim3(512),  dim3(256), 0, stream, Xq, Xk, P);
    hipLaunchKernelGGL(k0_basis,   dim3(256),  dim3(256), 0, stream, basis);
    hipLaunchKernelGGL(k2b_p3,     dim3(512),  dim3(256), 0, stream, P, Xk, PVG);
    hipLaunchKernelGGL(kwt,        dim3(512),  dim3(256), 0, stream, w1, w2, wT);
    hipLaunchKernelGGL(k2c_p4,     dim3(512),  dim3(256), 0, stream, PVG, wT, XWThi, XWTlo);
    hipLaunchKernelGGL(k3_mfma,    dim3(2048), dim3(256), 0, stream, basis, XWThi, XWTlo, out);
}

// Round 13
// 213.100 us; speedup vs baseline: 1.1366x; 1.1220x over previous
//
#include <hip/hip_runtime.h>
#include <math.h>

// FourierCrossAttention: B=16, L=4096, H=8, E=EO=64, MODES=64 (lowest)
// R13 = R12 with the macro-expansion compile error fixed (statement macro
// passed unparenthesized; gld16 uses direct addrspace casts).
// k1: global_load_lds staging (no VGPR round-trip) + counted vmcnt(8)/(4)
// barriers (never drain) + both-sides XOR swizzle on the raw buffer.
// Arithmetic identical to R9/R10 (fold + fragment-major A + xT).

constexpr float TWOPI_L = 1.5339807878856412e-3f;  // 2*pi/4096

typedef __attribute__((ext_vector_type(8))) short short8;
typedef __attribute__((ext_vector_type(4))) float f32x4;

__device__ __forceinline__ unsigned short f2bf(float f) {
    unsigned int u = __builtin_bit_cast(unsigned int, f);
    unsigned int r = (u + 0x7fffu + ((u >> 16) & 1u)) >> 16;
    return (unsigned short)r;
}
__device__ __forceinline__ float bf2f(unsigned short h) {
    unsigned int u = ((unsigned int)h) << 16;
    return __builtin_bit_cast(float, u);
}
__device__ __forceinline__ unsigned int cvtpk(float a, float b) {
    unsigned int r;
    asm("v_cvt_pk_bf16_f32 %0, %1, %2" : "=v"(r) : "v"(a), "v"(b));
    return r;
}
// async global->LDS, 16B per lane, dest = wave-uniform base + lane*16
__device__ __forceinline__ void gld16(const float* g, void* l) {
    __builtin_amdgcn_global_load_lds(
        (const __attribute__((address_space(1))) void*)(g),
        (__attribute__((address_space(3))) void*)(l),
        16, 0, 0);
}
// raw-buffer swizzle mask (float4-quad index XOR), row-local 0..63
#define MSKR(r) (((((r) & 7)) << 1) | ((((r) >> 3)) & 1))

// ---------------- K0: folded DFT twiddle tables, fragment-major (R9 layout) ----------------
// r_tab = rb*16+l15: 0..63 even modes (m=2*(r>>1)), 64..127 odd; c=r&1 (Re/-sin).
// addr = (kt*8 + rb)*512 + l15*32 + lg*8, t = kt*32 + ... (t < 2048).
__global__ __launch_bounds__(256) void k0_twiddle(unsigned short* __restrict__ Whi,
                                                  unsigned short* __restrict__ Wlo) {
    const int idx = blockIdx.x * 256 + threadIdx.x;   // 32768 threads
    const int kt = idx >> 9;            // 0..63
    const int rb = (idx >> 6) & 7;      // 0..7
    const int l15 = (idx >> 2) & 15;    // 0..15
    const int lg = idx & 3;             // 0..3
    const int r_tab = rb * 16 + l15;
    int m, c;
    if (r_tab < 64) { m = (r_tab >> 1) * 2;              c = r_tab & 1; }
    else            { m = (((r_tab - 64) >> 1) * 2) + 1; c = r_tab & 1; }
    const int addr = (kt * 8 + rb) * 512 + l15 * 32 + lg * 8;
    unsigned short hbuf[8], lbuf[8];
#pragma unroll
    for (int j = 0; j < 8; ++j) {
        const int t = kt * 32 + lg * 8 + j;
        float sv, cv;
        sincosf((float)((m * t) & 4095) * TWOPI_L, &sv, &cv);
        const float v = c ? -sv : cv;
        const unsigned short hi = f2bf(v);
        hbuf[j] = hi;
        lbuf[j] = f2bf(v - bf2f(hi));
    }
    *(uint4*)(Whi + addr) = *(uint4*)hbuf;
    *(uint4*)(Wlo + addr) = *(uint4*)lbuf;
}

// ---------------- K0b: irfft basis (bf16 hi only), written into ws (ex-Xq) ----------------
__global__ __launch_bounds__(256) void k0_basis(unsigned short* __restrict__ basis) {
    const int idx = blockIdx.x * 256 + threadIdx.x;   // 65536 threads x 4 pairs
    const int p0 = idx << 2;                          // (t,m) pair index
    const int t = p0 >> 6;
    unsigned int pk[4];
#pragma unroll
    for (int j = 0; j < 4; ++j) {
        const int m = (p0 & 63) + j;
        float sv, cv;
        sincosf((float)((m * t) & 4095) * TWOPI_L, &sv, &cv);
        const float c = (m == 0) ? 1.0f : 2.0f * cv;
        const float s = (m == 0) ? 0.0f : -2.0f * sv;
        pk[j] = (unsigned int)f2bf(c) | ((unsigned int)f2bf(s) << 16);
    }
    *(uint4*)(basis + (size_t)t * 128u + ((p0 & 63) << 1)) =
        make_uint4(pk[0], pk[1], pk[2], pk[3]);
}

// ---------------- K1: gll-staged folded MFMA DFT. C[128 rows][64 e], 16 tiles/block (S=4) ----------------
__global__ __launch_bounds__(256, 3) void k1_mfma(const float* __restrict__ q,
                                                  const float* __restrict__ kin,
                                                  const unsigned short* __restrict__ Whi,
                                                  const unsigned short* __restrict__ Wlo,
                                                  float* __restrict__ Xq, float* __restrict__ Xk,
                                                  float* __restrict__ Pq, float* __restrict__ Pk)
{
    __shared__ float raw[2][64][64];            // [buf][row: 32 t + 32 companion][64 e], 32 KB
    __shared__ unsigned short xT[4][64][40];    // xp_hi/xp_lo/xm_hi/xm_lo [e][t pad 40], 20.5 KB

    const int tid = threadIdx.x;
    const int bid = blockIdx.x;
    const int bh = bid >> 3, src = (bid >> 2) & 1, seg = bid & 3;
    const int b = bh >> 3, h = bh & 7;
    const float* __restrict__ x = src ? kin : q;
    const float* xb = x + (size_t)b * 2097152u + (size_t)h * 64u;

    const int wid = tid >> 6, lane = tid & 63;
    const int l15 = lane & 15, lg = lane >> 4;
    const int fp = (tid & 15) * 2;       // convert: t-pair rows fp, fp+1
    const int eqs = tid >> 4;            // convert: e-quad 0..15
    const int sel = (wid >> 1) * 2;      // waves 0,1: xp; waves 2,3: xm

    f32x4 acc[2][4];
#pragma unroll
    for (int mt = 0; mt < 2; ++mt)
#pragma unroll
        for (int nt = 0; nt < 4; ++nt)
            acc[mt][nt] = (f32x4){0.f, 0.f, 0.f, 0.f};

    // DMA one 16KB tile (64 rows x 256B): wave w issues 4 x gld16 (1KB each).
    // Global source pre-swizzled by MSKR so linear LDS holds swizzled quads.
#define K1_STAGE(IT, NXT) do {                                                  \
    const int t0_ = (seg * 16 + (IT)) * 32;                                     \
    _Pragma("unroll")                                                           \
    for (int j = 0; j < 4; ++j) {                                               \
        const int c_ = wid * 4 + j;                                             \
        const int rl_ = 4 * c_ + (lane >> 4);                                   \
        const int t_ = t0_ + (rl_ & 31) + ((rl_ >> 5) << 11);                   \
        const int sq_ = (lane & 15) ^ MSKR(rl_);                                \
        gld16(xb + (size_t)t_ * 512u + (size_t)(sq_ * 4), &raw[NXT][c_ * 4][0]); \
    }                                                                           \
} while (0)

#define K1_TILE(IT, CUR, STAGE_STMT, VMC) do {                                  \
    short8 Ah[2], Al[2];                                                        \
    const int ksg_ = seg * 16 + (IT);                                           \
    _Pragma("unroll")                                                           \
    for (int mt = 0; mt < 2; ++mt) {                                            \
        const size_t o_ = (size_t)((ksg_ * 8 + (wid * 2 + mt)) * 512 + l15 * 32 + lg * 8); \
        Ah[mt] = *(const short8*)(Whi + o_);                                    \
        Al[mt] = *(const short8*)(Wlo + o_);                                    \
    }                                                                           \
    __builtin_amdgcn_sched_barrier(0);  /* keep A-loads older than next DMA */  \
    STAGE_STMT;                                                                 \
    asm volatile("s_waitcnt vmcnt(" #VMC ")\n\ts_barrier" ::: "memory");        \
    {   /* convert raw[CUR] -> xT (fold + hi/lo cvtpk), R9 arithmetic */        \
        float rs[16];                                                           \
        *(f32x4*)&rs[0]  = *(const f32x4*)&raw[CUR][fp     ][(eqs ^ MSKR(fp))      * 4]; \
        *(f32x4*)&rs[4]  = *(const f32x4*)&raw[CUR][fp + 1 ][(eqs ^ MSKR(fp + 1))  * 4]; \
        *(f32x4*)&rs[8]  = *(const f32x4*)&raw[CUR][fp + 32][(eqs ^ MSKR(fp + 32)) * 4]; \
        *(f32x4*)&rs[12] = *(const f32x4*)&raw[CUR][fp + 33][(eqs ^ MSKR(fp + 33)) * 4]; \
        _Pragma("unroll")                                                       \
        for (int ee = 0; ee < 4; ++ee) {                                        \
            const float a0 = rs[ee], a1 = rs[4 + ee];                           \
            const float c0 = rs[8 + ee], c1 = rs[12 + ee];                      \
            const float xp0 = a0 + c0, xp1 = a1 + c1;                           \
            const float xm0 = a0 - c0, xm1 = a1 - c1;                           \
            const int e_ = eqs * 4 + ee;                                        \
            const unsigned int php = cvtpk(xp0, xp1);                           \
            const float ph0 = __builtin_bit_cast(float, php << 16);             \
            const float ph1 = __builtin_bit_cast(float, php & 0xffff0000u);     \
            const unsigned int plp = cvtpk(xp0 - ph0, xp1 - ph1);               \
            const unsigned int mhp = cvtpk(xm0, xm1);                           \
            const float mh0 = __builtin_bit_cast(float, mhp << 16);             \
            const float mh1 = __builtin_bit_cast(float, mhp & 0xffff0000u);     \
            const unsigned int mlp = cvtpk(xm0 - mh0, xm1 - mh1);               \
            *(unsigned int*)&xT[0][e_][fp] = php;                               \
            *(unsigned int*)&xT[1][e_][fp] = plp;                               \
            *(unsigned int*)&xT[2][e_][fp] = mhp;                               \
            *(unsigned int*)&xT[3][e_][fp] = mlp;                               \
        }                                                                       \
    }                                                                           \
    asm volatile("s_waitcnt lgkmcnt(0)\n\ts_barrier" ::: "memory");             \
    {   /* MFMA: A (L2 fragment-major) x xT, 3-pass hi/lo, R9 order */          \
        const unsigned short* sh = &xT[sel][0][0];                              \
        const unsigned short* sl = &xT[sel + 1][0][0];                          \
        _Pragma("unroll")                                                       \
        for (int nt = 0; nt < 4; ++nt) {                                        \
            const int ri = (nt * 16 + l15) * 40 + 8 * lg;                       \
            const short8 Bh = *(const short8*)(sh + ri);                        \
            const short8 Bl = *(const short8*)(sl + ri);                        \
            _Pragma("unroll")                                                   \
            for (int mt = 0; mt < 2; ++mt)                                      \
                acc[mt][nt] = __builtin_amdgcn_mfma_f32_16x16x32_bf16(Ah[mt], Bh, acc[mt][nt], 0, 0, 0); \
            _Pragma("unroll")                                                   \
            for (int mt = 0; mt < 2; ++mt)                                      \
                acc[mt][nt] = __builtin_amdgcn_mfma_f32_16x16x32_bf16(Ah[mt], Bl, acc[mt][nt], 0, 0, 0); \
            _Pragma("unroll")                                                   \
            for (int mt = 0; mt < 2; ++mt)                                      \
                acc[mt][nt] = __builtin_amdgcn_mfma_f32_16x16x32_bf16(Al[mt], Bh, acc[mt][nt], 0, 0, 0); \
        }                                                                       \
    }                                                                           \
} while (0)

    K1_STAGE(0, 0);
    for (int it = 0; it < 15; ++it) {
        // queue at vmcnt: [gll(it) 4][A(it) 4][gll(it+1) 4] -> vmcnt(8) waits gll(it)
        K1_TILE(it, (it & 1), K1_STAGE(it + 1, (it + 1) & 1), 8);
    }
    // epilogue tile 15: no further stage; queue [gll(15) 4][A(15) 4] -> vmcnt(4)
    K1_TILE(15, 1, (void)0, 4);

#undef K1_TILE
#undef K1_STAGE

    // C-write (R9 verified mapping): X[e][128] layout unchanged downstream.
    float* Xd;
    if (seg == 0) Xd = src ? Xk : Xq;
    else          Xd = (src ? Pk : Pq) + (size_t)(seg - 1) * 1048576u;
    Xd += (size_t)bh * 8192u;
    const int oddw = wid >> 1;
    const int wb = wid & 1;
#pragma unroll
    for (int mt = 0; mt < 2; ++mt) {
        const int r0 = (wb * 2 + mt) * 32 + 8 * lg + 2 * oddw;
#pragma unroll
        for (int nt = 0; nt < 4; ++nt) {
            const int e = nt * 16 + l15;
            *(float2*)(Xd + (size_t)e * 128u + r0) =
                make_float2(acc[mt][nt][0], acc[mt][nt][1]);
            *(float2*)(Xd + (size_t)e * 128u + r0 + 4) =
                make_float2(acc[mt][nt][2], acc[mt][nt][3]);
        }
    }
}

// ---------------- K1b: reduce the 3 K-split partial sets into main ----------------
__global__ __launch_bounds__(256) void k1_reduce(float* __restrict__ Xq, const float* __restrict__ Pq,
                                                 float* __restrict__ Xk, const float* __restrict__ Pk) {
    const int i = blockIdx.x * 256 + threadIdx.x;   // 262144 float4s per array
    float4* a = (float4*)Xq;
    float4* c = (float4*)Xk;
    float4 v = a[i], w = c[i];
#pragma unroll
    for (int s = 0; s < 3; ++s) {
        const float4 p = ((const float4*)(Pq + (size_t)s * 1048576u))[i];
        const float4 r = ((const float4*)(Pk + (size_t)s * 1048576u))[i];
        v.x += p.x; v.y += p.y; v.z += p.z; v.w += p.w;
        w.x += r.x; w.y += r.y; w.z += r.z; w.w += r.w;
    }
    a[i] = v;
    c[i] = w;
}

// ---------------- K2a: P1  xqk = Xq^T . Xk (complex), tanh -> P[bh][y][2x] ----------------
__global__ __launch_bounds__(256) void k2a_p1(const float* __restrict__ Xq,
                                              const float* __restrict__ Xk,
                                              float* __restrict__ P)
{
    const int blk = blockIdx.x;
    const int bh = blk >> 2, xt = blk & 3;
    __shared__ float sQ[64 * 32];    // [e][2x-slice]
    __shared__ float sK[64 * 128];   // [e][2y]
    const int tid = threadIdx.x;
    const float* Xqb = Xq + (size_t)bh * 8192u;
    const float* Xkb = Xk + (size_t)bh * 8192u;

#pragma unroll
    for (int p = 0; p < 2; ++p) {
        const int f4 = tid + p * 256;           // 512 float4s
        const int row = f4 >> 3, c4 = f4 & 7;
        *(float4*)&sQ[row * 32 + c4 * 4] = *(const float4*)(Xqb + row * 128 + xt * 32 + c4 * 4);
    }
#pragma unroll
    for (int p = 0; p < 8; ++p) {
        const int f4 = tid + p * 256;           // 2048 float4s
        *(float4*)&sK[f4 * 4] = *(const float4*)(Xkb + f4 * 4);
    }
    __syncthreads();

    const int xg = tid & 15, yg = tid >> 4;
    float aR[4] = {0.f, 0.f, 0.f, 0.f}, aI[4] = {0.f, 0.f, 0.f, 0.f};
#pragma unroll 8
    for (int e = 0; e < 64; ++e) {
        const float2 qv = *(const float2*)&sQ[e * 32 + 2 * xg];
        const float4 k0 = *(const float4*)&sK[e * 128 + 8 * yg];
        const float4 k1v = *(const float4*)&sK[e * 128 + 8 * yg + 4];
        aR[0] += qv.x * k0.x - qv.y * k0.y;   aI[0] += qv.x * k0.y + qv.y * k0.x;
        aR[1] += qv.x * k0.z - qv.y * k0.w;   aI[1] += qv.x * k0.w + qv.y * k0.z;
        aR[2] += qv.x * k1v.x - qv.y * k1v.y; aI[2] += qv.x * k1v.y + qv.y * k1v.x;
        aR[3] += qv.x * k1v.z - qv.y * k1v.w; aI[3] += qv.x * k1v.w + qv.y * k1v.z;
    }
    float* Pb = P + (size_t)bh * 8192u;
    const int x_abs = xt * 16 + xg;
#pragma unroll
    for (int j = 0; j < 4; ++j) {
        const int y = 4 * yg + j;
        *(float2*)(Pb + (size_t)y * 128u + 2 * x_abs) =
            make_float2(tanhf(aR[j]), tanhf(aI[j]));
    }
}

// ---------------- K2b: P3  PV = P . Xk (complex over y) -> PVG[h][m][c][b][e] ----------------
__global__ __launch_bounds__(256) void k2b_p3(const float* __restrict__ P,
                                              const float* __restrict__ Xk,
                                              float* __restrict__ PVG)
{
    const int blk = blockIdx.x;
    const int bh = blk >> 2, et = blk & 3;
    const int b = bh >> 3, h = bh & 7;
    __shared__ float sP[64 * 128];   // [y][2x]
    __shared__ float sKe[16 * 132];  // [e_loc][2y] pad->132
    const int tid = threadIdx.x;
    const float* Pb = P + (size_t)bh * 8192u;
    const float* Xkb = Xk + (size_t)bh * 8192u + (size_t)(et * 16) * 128u;

#pragma unroll
    for (int p = 0; p < 8; ++p) {
        const int f4 = tid + p * 256;
        *(float4*)&sP[f4 * 4] = *(const float4*)(Pb + f4 * 4);
    }
#pragma unroll
    for (int p = 0; p < 2; ++p) {
        const int f4 = tid + p * 256;           // 512 float4s
        const int row = f4 >> 5, c4 = f4 & 31;
        *(float4*)&sKe[row * 132 + c4 * 4] = *(const float4*)(Xkb + row * 128 + c4 * 4);
    }
    __syncthreads();

    const int xg = tid & 15, el = tid >> 4;
    float aR[4] = {0.f, 0.f, 0.f, 0.f}, aI[4] = {0.f, 0.f, 0.f, 0.f};
#pragma unroll 8
    for (int y = 0; y < 64; ++y) {
        const float2 kv = *(const float2*)&sKe[el * 132 + 2 * y];
        const float4 p0 = *(const float4*)&sP[y * 128 + 8 * xg];
        const float4 p1 = *(const float4*)&sP[y * 128 + 8 * xg + 4];
        aR[0] += p0.x * kv.x - p0.y * kv.y;   aI[0] += p0.x * kv.y + p0.y * kv.x;
        aR[1] += p0.z * kv.x - p0.w * kv.y;   aI[1] += p0.z * kv.y + p0.w * kv.x;
        aR[2] += p1.x * kv.x - p1.y * kv.y;   aI[2] += p1.x * kv.y + p1.y * kv.x;
        aR[3] += p1.z * kv.x - p1.w * kv.y;   aI[3] += p1.z * kv.y + p1.w * kv.x;
    }
    const int e_abs = et * 16 + el;
    float* base = PVG + (size_t)h * 131072u;   // per h: 64m*2c*16b*64e
#pragma unroll
    for (int j = 0; j < 4; ++j) {
        const int m = 4 * xg + j;
        base[(size_t)m * 2048u + 0u    + (size_t)b * 64u + e_abs] = aR[j];
        base[(size_t)m * 2048u + 1024u + (size_t)b * 64u + e_abs] = aI[j];
    }
}

// ---------------- KWT: w1/w2 -> wT[h][m][e][2o] ----------------
__global__ __launch_bounds__(256) void kwt(const float* __restrict__ w1,
                                           const float* __restrict__ w2,
                                           float* __restrict__ wT)
{
    const int blk = blockIdx.x;     // h*64 + e
    const int h = blk >> 6, e = blk & 63;
    const int tid = threadIdx.x;
    const int m = tid & 63, oq = tid >> 6;   // o = oq*16 + i
    const float* w1b = w1 + ((size_t)(h * 64 + e)) * 4096u;
    const float* w2b = w2 + ((size_t)(h * 64 + e)) * 4096u;
    float buf[32];
#pragma unroll
    for (int i = 0; i < 16; ++i) {
        const int o = oq * 16 + i;
        buf[2 * i]     = w1b[o * 64 + m];
        buf[2 * i + 1] = w2b[o * 64 + m];
    }
    float* dst = wT + (((size_t)(h * 64 + m)) * 64u + e) * 128u + oq * 32;
#pragma unroll
    for (int i = 0; i < 8; ++i)
        *(float4*)(dst + i * 4) = *(float4*)&buf[i * 4];
}

// ---------------- K2c: P4  XW = PV . (w1 + i w2) -> XWT hi/lo bf16 ----------------
__global__ __launch_bounds__(256) void k2c_p4(const float* __restrict__ PVG,
                                              const float* __restrict__ wT,
                                              unsigned short* __restrict__ XWThi,
                                              unsigned short* __restrict__ XWTlo)
{
    const int blk = blockIdx.x;       // h*64 + m
    const int h = blk >> 6, m = blk & 63;
    __shared__ float sA[32 * 68];     // [c*16+b][e pad 68]
    __shared__ float sW[64 * 128];    // [e][2o]
    const int tid = threadIdx.x;
    const float* Ab = PVG + (size_t)h * 131072u + (size_t)m * 2048u;
    const float* Wb = wT + ((size_t)h * 64u + m) * 8192u;

#pragma unroll
    for (int p = 0; p < 2; ++p) {
        const int f4 = tid + p * 256;           // 512 float4s
        const int row = f4 >> 4, e0 = (f4 & 15) * 4;
        *(float4*)&sA[row * 68 + e0] = *(const float4*)(Ab + row * 64 + e0);
    }
#pragma unroll
    for (int p = 0; p < 8; ++p) {
        const int f4 = tid + p * 256;
        *(float4*)&sW[f4 * 4] = *(const float4*)(Wb + f4 * 4);
    }
    __syncthreads();

    const int og = tid & 15, b = tid >> 4;
    float aR[4] = {0.f, 0.f, 0.f, 0.f}, aI[4] = {0.f, 0.f, 0.f, 0.f};
#pragma unroll 8
    for (int e = 0; e < 64; ++e) {
        const float pR = sA[b * 68 + e];
        const float pI = sA[(16 + b) * 68 + e];
        const float4 w0 = *(const float4*)&sW[e * 128 + 8 * og];
        const float4 w1v = *(const float4*)&sW[e * 128 + 8 * og + 4];
        aR[0] += pR * w0.x - pI * w0.y;   aI[0] += pR * w0.y + pI * w0.x;
        aR[1] += pR * w0.z - pI * w0.w;   aI[1] += pR * w0.w + pI * w0.z;
        aR[2] += pR * w1v.x - pI * w1v.y; aI[2] += pR * w1v.y + pI * w1v.x;
        aR[3] += pR * w1v.z - pI * w1v.w; aI[3] += pR * w1v.w + pI * w1v.z;
    }
    const int bh = b * 8 + h;
    unsigned short* Th = XWThi + (size_t)bh * 8192u;
    unsigned short* Tl = XWTlo + (size_t)bh * 8192u;
#pragma unroll
    for (int j = 0; j < 4; ++j) {
        const int o = 4 * og + j;
        const unsigned int hp = cvtpk(aR[j], aI[j]);
        const float hR = __builtin_bit_cast(float, hp << 16);
        const float hI = __builtin_bit_cast(float, hp & 0xffff0000u);
        const unsigned int lp = cvtpk(aR[j] - hR, aI[j] - hI);
        *(unsigned int*)(Th + (size_t)o * 128u + 2 * m) = hp;
        *(unsigned int*)(Tl + (size_t)o * 128u + 2 * m) = lp;
    }
}

// ---------------- K3: MFMA irfft  out[4096t x 64o] = basis[4096x128] * XWT^T ----------------
__global__ __launch_bounds__(256, 3) void k3_mfma(const unsigned short* __restrict__ basis,
                                                  const unsigned short* __restrict__ XWThi,
                                                  const unsigned short* __restrict__ XWTlo,
                                                  float* __restrict__ out)
{
    const int bid = blockIdx.x;
    const int bh = bid >> 4, tc = bid & 15;
    const int b = bh >> 3, h = bh & 7;
    const int tid = threadIdx.x;
    const int wid = tid >> 6, lane = tid & 63;
    const int l15 = lane & 15, lg = lane >> 4;

    const int t0 = tc * 256 + wid * 64;
    const unsigned short* Th = XWThi + (size_t)bh * 8192u;
    const unsigned short* Tl = XWTlo + (size_t)bh * 8192u;

    f32x4 acc[4][4];
#pragma unroll
    for (int mt = 0; mt < 4; ++mt)
#pragma unroll
        for (int nt = 0; nt < 4; ++nt)
            acc[mt][nt] = (f32x4){0.f, 0.f, 0.f, 0.f};

#pragma unroll
    for (int ks = 0; ks < 4; ++ks) {
        const int ko = ks * 32 + 8 * lg;
        short8 A[4], Bh[4], Bl[4];
#pragma unroll
        for (int mt = 0; mt < 4; ++mt)
            A[mt] = *(const short8*)(basis + (size_t)(t0 + mt * 16 + l15) * 128u + ko);
#pragma unroll
        for (int nt = 0; nt < 4; ++nt) {
            Bh[nt] = *(const short8*)(Th + (size_t)(nt * 16 + l15) * 128u + ko);
            Bl[nt] = *(const short8*)(Tl + (size_t)(nt * 16 + l15) * 128u + ko);
        }
#pragma unroll
        for (int mt = 0; mt < 4; ++mt)
#pragma unroll
            for (int nt = 0; nt < 4; ++nt)
                acc[mt][nt] = __builtin_amdgcn_mfma_f32_16x16x32_bf16(A[mt], Bh[nt], acc[mt][nt], 0, 0, 0);
#pragma unroll
        for (int mt = 0; mt < 4; ++mt)
#pragma unroll
            for (int nt = 0; nt < 4; ++nt)
                acc[mt][nt] = __builtin_amdgcn_mfma_f32_16x16x32_bf16(A[mt], Bl[nt], acc[mt][nt], 0, 0, 0);
    }

    const float scale = 9.313225746154785e-10f;  // 2^-30
#pragma unroll
    for (int mt = 0; mt < 4; ++mt)
#pragma unroll
        for (int nt = 0; nt < 4; ++nt) {
            const int o = nt * 16 + l15;
#pragma unroll
            for (int j = 0; j < 4; ++j) {
                const int t = t0 + mt * 16 + 4 * lg + j;
                out[((size_t)(b * 4096 + t) * 8u + (size_t)h) * 64u + o] = acc[mt][nt][j] * scale;
            }
        }
}

extern "C" void kernel_launch(void* const* d_in, const int* in_sizes, int n_in,
                              void* d_out, int out_size, void* d_ws, size_t ws_size,
                              hipStream_t stream) {
    (void)in_sizes; (void)n_in; (void)out_size; (void)ws_size;
    const float* q  = (const float*)d_in[0];
    const float* k  = (const float*)d_in[1];
    // d_in[2] = v: unused by the reference forward
    const float* w1 = (const float*)d_in[3];
    const float* w2 = (const float*)d_in[4];
    float* out = (float*)d_out;

    // ws (12 MB): Xq [0,4MB) fl, Xk [4,8MB) fl, XWThi/lo [8,12MB) as bf16
    float* ws = (float*)d_ws;
    float* Xq = ws;
    float* Xk = ws + 1048576;
    unsigned short* XWThi = (unsigned short*)(ws + 2097152);   // 1,048,576 shorts
    unsigned short* XWTlo = XWThi + 1048576;
    unsigned short* basis = (unsigned short*)ws;               // overlays Xq AFTER k2a

    // d_out scratch (33.5M floats; all regions dead before k3 overwrites):
    unsigned short* Whi = (unsigned short*)out;                // 262,144 shorts (folded table)
    unsigned short* Wlo = Whi + 262144;                        // 262,144 shorts
    float* Pq  = out + 524288;                                 // 3 x 1M fl
    float* Pk  = out + 3670016;                                // 3 x 1M fl -> ends 6,815,744
    float* P   = out + 16777216;                               // 1M fl  (tanh'd xqk, [y][2x])
    float* wT  = out + 17825792;                               // 4M fl  [h][m][e][2o] -> 22,020,096
    float* PVG = out + 22020096;                               // 1M fl  [h][m][c][b][e]

    hipLaunchKernelGGL(k0_twiddle, dim3(128),  dim3(256), 0, stream, Whi, Wlo);
    hipLaunchKernelGGL(k1_mfma,    dim3(1024), dim3(256), 0, stream, q, k, Whi, Wlo, Xq, Xk, Pq, Pk);
    hipLaunchKernelGGL(k1_reduce,  dim3(1024), dim3(256), 0, stream, Xq, Pq, Xk, Pk);
    hipLaunchKernelGGL(k2a_p1,     dim3(512),  dim3(256), 0, stream, Xq, Xk, P);
    hipLaunchKernelGGL(k0_basis,   dim3(256),  dim3(256), 0, stream, basis);
    hipLaunchKernelGGL(k2b_p3,     dim3(512),  dim3(256), 0, stream, P, Xk, PVG);
    hipLaunchKernelGGL(kwt,        dim3(512),  dim3(256), 0, stream, w1, w2, wT);
    hipLaunchKernelGGL(k2c_p4,     dim3(512),  dim3(256), 0, stream, PVG, wT, XWThi, XWTlo);
    hipLaunchKernelGGL(k3_mfma,    dim3(2048), dim3(256), 0, stream, basis, XWThi, XWTlo, out);
}